// Round 9
// baseline (232.096 us; speedup 1.0000x reference)
//
#include <hip/hip_runtime.h>
#include <stdint.h>

typedef __attribute__((ext_vector_type(8))) short short8;   // 8 bf16 (4 VGPRs)
typedef __attribute__((ext_vector_type(4))) float f32x4;

#define LDS_AS __attribute__((address_space(3)))
#define GLOB_AS __attribute__((address_space(1)))

__device__ __forceinline__ void gload_lds16(const void* g, void* l) {
    __builtin_amdgcn_global_load_lds((const GLOB_AS uint32_t*)g,
                                     (LDS_AS uint32_t*)l, 16, 0, 0);
}

__device__ __forceinline__ unsigned short f2bf(float f) {
    uint32_t u = __builtin_bit_cast(uint32_t, f);
    u += 0x7fffu + ((u >> 16) & 1u);
    return (unsigned short)(u >> 16);
}
__device__ __forceinline__ float bf2f(unsigned short u) {
    uint32_t v = ((uint32_t)u) << 16;
    return __builtin_bit_cast(float, v);
}

#define WAIT_VM(N)   asm volatile("s_waitcnt vmcnt(" #N ")" ::: "memory")
#define WAIT_LGKM0() asm volatile("s_waitcnt lgkmcnt(0)" ::: "memory")
#define BAR()        asm volatile("s_barrier" ::: "memory")
#define FENCE()      __builtin_amdgcn_sched_barrier(0)

// ------------- fused fp32 -> bf16 convert (x, qkv_w, proj_w) -------------
__global__ void cvt3_kernel(const float* __restrict__ s0,
                            const float* __restrict__ s1,
                            const float* __restrict__ s2,
                            unsigned short* __restrict__ d0,
                            unsigned short* __restrict__ d1,
                            unsigned short* __restrict__ d2) {
    long e = ((long)blockIdx.x * blockDim.x + threadIdx.x) * 4;
    const float* s; unsigned short* d; long off;
    if (e < 8388608)        { s = s0; d = d0; off = e; }
    else if (e < 11534336)  { s = s1; d = d1; off = e - 8388608; }
    else                    { s = s2; d = d2; off = e - 11534336; }
    float4 v = *(const float4*)(s + off);
    ushort4 o;
    o.x = f2bf(v.x); o.y = f2bf(v.y); o.z = f2bf(v.z); o.w = f2bf(v.w);
    *(ushort4*)(d + off) = o;
}

// ---------------- rope tables: cos/sin (2048 x 32) ----------------
__global__ void rope_tables(float* __restrict__ cosT, float* __restrict__ sinT) {
    int tid = blockIdx.x * blockDim.x + threadIdx.x;  // 65536
    int t = tid >> 5, i = tid & 31;
    float f = (i < 16) ? exp2f(-10.0f * (float)i / 15.0f) : 0.0f;
    float th = (float)t * f;
    cosT[tid] = cosf(th);
    sinT[tid] = sinf(th);
}

// ==== GEMM C[m,n]=sum_k A[m,k]*B[n,k], bf16, fp32 acc ====================
// 128x128 tile, BK=32, 4 waves (2Mx2N, 64x64/wave). Ring-3 LDS (3x16KB=48KB)
// -> 3 blocks/CU (the m132 lever: 2 blocks=508TF vs 3 blocks=874TF).
// k-major LDS layout: group g (16 rows) = 1KB at g*1024; row r, k-octet c:
// byte = (r>>4)*1024 + c*256 + (r&15)*16 -> wave frag reads are 1KB
// contiguous (conflict-free, no swizzle; verified r7). One barrier/tile;
// counted vmcnt(4): per wave, tile t's 4 loads (issued at t-2) retired
// BEFORE the top-of-t barrier; stage t+2 after it. Never drains until tail.
// MODE 1: qkv epilogue (q/k RMS+RoPE; v lerp -> vout + vbT). MODE 2: +bias.
template <int MODE>
__global__ __launch_bounds__(256, 3) void gemm128(
    const unsigned short* __restrict__ A, const unsigned short* __restrict__ B,
    int K,
    unsigned short* __restrict__ qbuf, unsigned short* __restrict__ kbuf,
    float* __restrict__ vout, unsigned short* __restrict__ vbT,
    const float* __restrict__ v1, const float* __restrict__ lambp,
    float* __restrict__ y, const float* __restrict__ bias,
    const float* __restrict__ cosT, const float* __restrict__ sinT)
{
    __shared__ __align__(16) char smem[49152];    // 3 slots x (A 8KB + B 8KB)
    const int tid = threadIdx.x, lane = tid & 63, w = tid >> 6;
    const int wr = w >> 1, wc = w & 1;
    const int lr = lane & 15, lh = lane >> 4;
    const long m0 = (long)blockIdx.x * 128;
    const long n0 = (long)blockIdx.y * 128;
    const int NT = K >> 5;                        // 32 K-steps
    const long rsb = (long)K * 2;

    // staging sources (k-major): lane fetches (row = w*16+lr, k-octet lh)
    const char* pa0 = (const char*)A + (m0 + w * 16 + lr) * rsb + lh * 16;
    const char* pa1 = pa0 + 64 * rsb;
    const char* pb0 = (const char*)B + (n0 + w * 16 + lr) * rsb + lh * 16;
    const char* pb1 = pb0 + 64 * rsb;

    auto STAGE = [&](int slot) {                  // 4 gload_lds / wave / tile
        char* d = smem + slot;
        gload_lds16(pa0, d + w * 1024);           // A group w
        gload_lds16(pa1, d + 4096 + w * 1024);    // A group w+4
        gload_lds16(pb0, d + 8192 + w * 1024);    // B group w
        gload_lds16(pb1, d + 12288 + w * 1024);   // B group w+4
        pa0 += 64; pa1 += 64; pb0 += 64; pb1 += 64;
    };

    const int fofs = lh * 256 + lr * 16;          // frag read offset in group

    f32x4 acc[4][4] = {};

    // prologue: T0 -> slot0, T1 -> slot1 (8 loads in flight)
    STAGE(0);
    STAGE(16384);

    int cs = 0, ss = 32768;                       // compute slot, stage slot
    for (int t = 0; t < NT; ++t) {
        if (t < NT - 1) WAIT_VM(4);               // retire own tile-t loads
        else            WAIT_VM(0);
        BAR();                                    // all waves: t-1 reads done
        FENCE();
        if (t + 2 < NT) STAGE(ss);                // overwrite slot read at t-1

        const char* cb = smem + cs;
        short8 af[4], bf[4];
        #pragma unroll
        for (int mi = 0; mi < 4; ++mi)
            af[mi] = *(const short8*)(cb + (wr * 4 + mi) * 1024 + fofs);
        #pragma unroll
        for (int nj = 0; nj < 4; ++nj)
            bf[nj] = *(const short8*)(cb + 8192 + (wc * 4 + nj) * 1024 + fofs);
        WAIT_LGKM0();
        FENCE();
        __builtin_amdgcn_s_setprio(1);
        #pragma unroll
        for (int mi = 0; mi < 4; ++mi)
            #pragma unroll
            for (int nj = 0; nj < 4; ++nj)
                acc[mi][nj] = __builtin_amdgcn_mfma_f32_16x16x32_bf16(
                    af[mi], bf[nj], acc[mi][nj], 0, 0, 0);
        __builtin_amdgcn_s_setprio(0);

        cs = (cs == 32768) ? 0 : cs + 16384;
        ss = (ss == 32768) ? 0 : ss + 16384;
    }

    // ---- epilogue: per-wave 64x64 at rows m0+wr*64, cols n0+wc*64 ----
    if constexpr (MODE == 1) {
        const long nbase = n0 + wc * 64;      // wave-uniform, 64-aligned
        const int kk = (int)(nbase >> 10);    // 0=q 1=k 2=v (uniform)
        const int h = (int)((nbase & 1023) >> 6);
        if (kk == 2) {
            float lam = lambp[0];
            #pragma unroll
            for (int i = 0; i < 4; ++i)
            #pragma unroll
            for (int j = 0; j < 4; ++j)
            #pragma unroll
            for (int r = 0; r < 4; ++r) {
                long m = m0 + wr * 64 + i * 16 + lh * 4 + r;
                int d = j * 16 + lr;
                int rem = h * 64 + d;
                long b_ = m >> 11, t = m & 2047;
                size_t idx = (((size_t)(b_ * 16 + h)) * 2048 + t) * 64 + d;
                float vv = v1[(size_t)m * 1024 + rem];
                float val = (1.0f - lam) * acc[i][j][r] + lam * vv;
                vout[idx] = val;
                vbT[(((size_t)(b_ * 16 + h)) * 64 + d) * 2048 + t] = f2bf(val);
            }
        } else {
            unsigned short* dst = (kk == 0) ? qbuf : kbuf;
            #pragma unroll
            for (int i = 0; i < 4; ++i)
            #pragma unroll
            for (int r = 0; r < 4; ++r) {
                float v0 = acc[i][0][r], v1_ = acc[i][1][r];
                float v2 = acc[i][2][r], v3 = acc[i][3][r];
                float ss_ = v0 * v0 + v1_ * v1_ + v2 * v2 + v3 * v3;
                ss_ += __shfl_xor(ss_, 1);
                ss_ += __shfl_xor(ss_, 2);
                ss_ += __shfl_xor(ss_, 4);
                ss_ += __shfl_xor(ss_, 8);
                float inv = rsqrtf(ss_ * (1.0f / 64.0f) + 1e-6f);
                float x0f = v0 * inv, x1f = v1_ * inv;
                float x2f = v2 * inv, x3f = v3 * inv;
                long m = m0 + wr * 64 + i * 16 + lh * 4 + r;
                int t = (int)(m & 2047);
                long b_ = m >> 11;
                float c0 = cosT[t * 32 + lr],      s0 = sinT[t * 32 + lr];
                float c1 = cosT[t * 32 + 16 + lr], s1 = sinT[t * 32 + 16 + lr];
                size_t rb = (((size_t)(b_ * 16 + h)) * 2048 + t) * 64;
                dst[rb + 0 * 16 + lr] = f2bf( x0f * c0 + x2f * s0);
                dst[rb + 1 * 16 + lr] = f2bf( x1f * c1 + x3f * s1);
                dst[rb + 2 * 16 + lr] = f2bf(-x0f * s0 + x2f * c0);
                dst[rb + 3 * 16 + lr] = f2bf(-x1f * s1 + x3f * c1);
            }
        }
    } else {
        #pragma unroll
        for (int i = 0; i < 4; ++i)
        #pragma unroll
        for (int j = 0; j < 4; ++j)
        #pragma unroll
        for (int r = 0; r < 4; ++r) {
            long m = m0 + wr * 64 + i * 16 + lh * 4 + r;
            long n = n0 + wc * 64 + j * 16 + lr;
            y[(size_t)m * 1024 + n] = acc[i][j][r] + bias[n];
        }
    }
}

// ---------------- flash attention, sliding window (round-4 proven) -------
__global__ __launch_bounds__(512, 2) void attn_kernel(
    const unsigned short* __restrict__ qn, const unsigned short* __restrict__ kn,
    const unsigned short* __restrict__ vtb, unsigned short* __restrict__ attn_out,
    const int* __restrict__ winp)
{
    __shared__ unsigned short Ks[2][64 * 64];    // [key][d], swizzled
    __shared__ unsigned short Vt[2][64 * 64];    // [d][key], swizzled
    __shared__ unsigned short Pl[8][16 * 72];    // per-wave P: [qrow][key]
    const int tid = threadIdx.x, lane = tid & 63, w = tid >> 6;
    const int lr = lane & 15, lh = lane >> 4;
    const int bh = blockIdx.x;                   // 0..63
    const int qt2 = blockIdx.y;                  // 0..15
    const int t0 = qt2 * 128;
    const int win = winp[0];
    const int qrow = t0 + w * 16;

    short8 qf[2];
    #pragma unroll
    for (int ks = 0; ks < 2; ++ks)
        qf[ks] = *(const short8*)&qn[((size_t)bh * 2048 + qrow + lr) * 64 + ks * 32 + lh * 8];

    const int srow = tid >> 3;
    const int scol = (tid & 7) ^ (srow & 7);
    const char* kg = (const char*)kn + ((size_t)bh * 2048 + srow) * 128 + scol * 16;
    const char* vg = (const char*)vtb + ((size_t)(bh * 64 + srow)) * 4096 + scol * 16;
    char* lk = (char*)&Ks[0][0] + w * 1024;
    char* lv = (char*)&Vt[0][0] + w * 1024;

    auto STAGE = [&](int buf, int j0) {
        gload_lds16(kg + (size_t)j0 * 128, lk + buf * 8192);
        gload_lds16(vg + (size_t)j0 * 2,   lv + buf * 8192);
    };

    f32x4 oacc[4] = {};
    float mrow[4], lrow[4];
    #pragma unroll
    for (int r = 0; r < 4; ++r) { mrow[r] = -1e30f; lrow[r] = 0.f; }

    const float C = 0.125f * 1.44269504f;   // scale * log2(e)
    const int kvt0 = max(0, t0 - win + 1) >> 6;
    const int kvt1 = (t0 + 127) >> 6;

    STAGE(0, kvt0 * 64);
    __syncthreads();
    for (int kvt = kvt0; kvt <= kvt1; ++kvt) {
        const int j0 = kvt * 64;
        const int buf = (kvt - kvt0) & 1;
        if (kvt < kvt1) STAGE(buf ^ 1, j0 + 64);

        if (j0 <= qrow + 15 && j0 + 63 >= qrow + 16 - win) {
            const char* ksb = (const char*)&Ks[buf][0];
            const char* vtb_ = (const char*)&Vt[buf][0];

            float sv[4][4];
            #pragma unroll
            for (int kt = 0; kt < 4; ++kt) {
                f32x4 s = {};
                #pragma unroll
                for (int ks = 0; ks < 2; ++ks) {
                    int row = kt * 16 + lr;
                    int off = row * 128 + (((ks * 4 + lh) ^ (row & 7)) * 16);
                    short8 kf = *(const short8*)(ksb + off);
                    s = __builtin_amdgcn_mfma_f32_16x16x32_bf16(qf[ks], kf, s, 0, 0, 0);
                }
                #pragma unroll
                for (int r = 0; r < 4; ++r) {
                    int qi = qrow + lh * 4 + r;
                    int ji = j0 + kt * 16 + lr;
                    bool ok = (ji <= qi) && (qi - ji < win);
                    sv[kt][r] = ok ? s[r] * C : -1e30f;
                }
            }

            float pn[4][4];
            #pragma unroll
            for (int r = 0; r < 4; ++r) {
                float tm = fmaxf(fmaxf(sv[0][r], sv[1][r]), fmaxf(sv[2][r], sv[3][r]));
                #pragma unroll
                for (int m = 1; m < 16; m <<= 1) tm = fmaxf(tm, __shfl_xor(tm, m));
                float nm = fmaxf(mrow[r], tm);
                float alpha = exp2f(mrow[r] - nm);
                float ps = 0.f;
                #pragma unroll
                for (int kt = 0; kt < 4; ++kt) {
                    float p = exp2f(sv[kt][r] - nm);
                    pn[kt][r] = p; ps += p;
                }
                #pragma unroll
                for (int m = 1; m < 16; m <<= 1) ps += __shfl_xor(ps, m);
                lrow[r] = lrow[r] * alpha + ps;
                mrow[r] = nm;
                #pragma unroll
                for (int dt = 0; dt < 4; ++dt) oacc[dt][r] *= alpha;
            }

            #pragma unroll
            for (int kt = 0; kt < 4; ++kt)
                #pragma unroll
                for (int r = 0; r < 4; ++r)
                    Pl[w][(lh * 4 + r) * 72 + kt * 16 + lr] = f2bf(pn[kt][r]);

            short8 pf[2];
            #pragma unroll
            for (int ks = 0; ks < 2; ++ks)
                pf[ks] = *(const short8*)&Pl[w][lr * 72 + ks * 32 + lh * 8];
            #pragma unroll
            for (int dt = 0; dt < 4; ++dt)
                #pragma unroll
                for (int ks = 0; ks < 2; ++ks) {
                    int row = dt * 16 + lr;
                    int off = row * 128 + (((ks * 4 + lh) ^ (row & 7)) * 16);
                    short8 vf = *(const short8*)(vtb_ + off);
                    oacc[dt] = __builtin_amdgcn_mfma_f32_16x16x32_bf16(pf[ks], vf, oacc[dt], 0, 0, 0);
                }
        }
        __syncthreads();
    }

    int b = bh >> 4, h = bh & 15;
    #pragma unroll
    for (int dt = 0; dt < 4; ++dt)
        #pragma unroll
        for (int r = 0; r < 4; ++r) {
            int t = qrow + lh * 4 + r;
            float o = oacc[dt][r] / lrow[r];
            attn_out[((size_t)b * 2048 + t) * 1024 + h * 64 + dt * 16 + lr] = f2bf(o);
        }
}

extern "C" void kernel_launch(void* const* d_in, const int* in_sizes, int n_in,
                              void* d_out, int out_size, void* d_ws, size_t ws_size,
                              hipStream_t stream) {
    const float* x    = (const float*)d_in[0];
    const float* v1   = (const float*)d_in[1];
    const float* qkvw = (const float*)d_in[2];
    const float* cpw  = (const float*)d_in[3];
    const float* cpb  = (const float*)d_in[4];
    const float* lamb = (const float*)d_in[5];
    const int*   winp = (const int*)d_in[6];

    float* y    = (float*)d_out;
    float* vout = y + (size_t)8192 * 1024;   // value output (B,H,T,64) fp32

    // V^T bf16 scratch lives in the y region of d_out; proj overwrites y after.
    unsigned short* vbT = (unsigned short*)y;

    char* ws = (char*)d_ws;
    unsigned short* xb   = (unsigned short*)(ws);                 // 16MB (reused as attn_out)
    unsigned short* Wb   = (unsigned short*)(ws + (16u << 20));   // 6MB
    unsigned short* Wp   = (unsigned short*)(ws + (22u << 20));   // 2MB
    unsigned short* qbuf = (unsigned short*)(ws + (24u << 20));   // 16MB
    unsigned short* kbuf = (unsigned short*)(ws + (40u << 20));   // 16MB
    float* cosT = (float*)(ws + (56u << 20));                     // 256KB
    float* sinT = (float*)(ws + (56u << 20) + (256u << 10));      // 256KB

    cvt3_kernel<<<12288, 256, 0, stream>>>(x, qkvw, cpw, xb, Wb, Wp);
    rope_tables<<<65536 / 256, 256, 0, stream>>>(cosT, sinT);

    gemm128<1><<<dim3(64, 24), 256, 0, stream>>>(xb, Wb, 1024,
        qbuf, kbuf, vout, vbT, v1, lamb, nullptr, nullptr, cosT, sinT);

    attn_kernel<<<dim3(64, 16), 512, 0, stream>>>(qbuf, kbuf, vbT, xb, winp);

    gemm128<2><<<dim3(64, 8), 256, 0, stream>>>(xb, Wp, 1024,
        nullptr, nullptr, nullptr, nullptr, nullptr, nullptr, y, cpb, nullptr, nullptr);
}

// Round 10
// 229.844 us; speedup vs baseline: 1.0098x; 1.0098x over previous
//
#include <hip/hip_runtime.h>
#include <stdint.h>

typedef __attribute__((ext_vector_type(8))) short short8;   // 8 bf16 (4 VGPRs)
typedef __attribute__((ext_vector_type(4))) float f32x4;

#define LDS_AS __attribute__((address_space(3)))
#define GLOB_AS __attribute__((address_space(1)))

__device__ __forceinline__ void gload_lds16(const void* g, void* l) {
    __builtin_amdgcn_global_load_lds((const GLOB_AS uint32_t*)g,
                                     (LDS_AS uint32_t*)l, 16, 0, 0);
}

__device__ __forceinline__ unsigned short f2bf(float f) {
    uint32_t u = __builtin_bit_cast(uint32_t, f);
    u += 0x7fffu + ((u >> 16) & 1u);
    return (unsigned short)(u >> 16);
}
__device__ __forceinline__ float bf2f(unsigned short u) {
    uint32_t v = ((uint32_t)u) << 16;
    return __builtin_bit_cast(float, v);
}

#define WAIT_VM(N)   asm volatile("s_waitcnt vmcnt(" #N ")" ::: "memory")
#define WAIT_LGKM0() asm volatile("s_waitcnt lgkmcnt(0)" ::: "memory")
#define BAR()        asm volatile("s_barrier" ::: "memory")
#define FENCE()      __builtin_amdgcn_sched_barrier(0)

// ------------- fused fp32 -> bf16 convert (x, qkv_w, proj_w) -------------
__global__ void cvt3_kernel(const float* __restrict__ s0,
                            const float* __restrict__ s1,
                            const float* __restrict__ s2,
                            unsigned short* __restrict__ d0,
                            unsigned short* __restrict__ d1,
                            unsigned short* __restrict__ d2) {
    long e = ((long)blockIdx.x * blockDim.x + threadIdx.x) * 4;
    const float* s; unsigned short* d; long off;
    if (e < 8388608)        { s = s0; d = d0; off = e; }
    else if (e < 11534336)  { s = s1; d = d1; off = e - 8388608; }
    else                    { s = s2; d = d2; off = e - 11534336; }
    float4 v = *(const float4*)(s + off);
    ushort4 o;
    o.x = f2bf(v.x); o.y = f2bf(v.y); o.z = f2bf(v.z); o.w = f2bf(v.w);
    *(ushort4*)(d + off) = o;
}

// ---------------- rope tables: cos/sin (2048 x 32) ----------------
__global__ void rope_tables(float* __restrict__ cosT, float* __restrict__ sinT) {
    int tid = blockIdx.x * blockDim.x + threadIdx.x;  // 65536
    int t = tid >> 5, i = tid & 31;
    float f = (i < 16) ? exp2f(-10.0f * (float)i / 15.0f) : 0.0f;
    float th = (float)t * f;
    cosT[tid] = cosf(th);
    sinT[tid] = sinf(th);
}

// ==== m201-style GEMM: BM=BN=256, BK=64, 8 waves (2Mx4N, 128x64/wave) ====
// LDS 128KB = 2 dbuf x (A 32KB + B 32KB). k-major group layout: group g
// (16 rows) at g*2048; within: ks*1024 + lh*256 + lr*16 -> wave-gload
// writes and frag reads are both 1KB contiguous (conflict-free, measured 0).
// Per K-tile 4 phases (C-quadrants, 16 MFMA each; 12/4/8/0 ds_reads), each:
// {reads; stage 1 half-tile (2 gloads); [vmcnt(4) @P3]; s_barrier;
//  lgkmcnt(0); sched_barrier; setprio(1); 16 MFMA; setprio(0); s_barrier}.
// Stage targets: P0:A0(t+1) P1:A1(t+1) P2:B0(t+2) P3:B1(t+2); the single
// vmcnt(4)@P3 retires A(t+1) with a 3-phase lead; drains only at tail.
// MODE 1: qkv epilogue (q/k RMS+RoPE; v lerp -> vout + vbT). MODE 2: +bias.
template <int MODE>
__global__ __launch_bounds__(512, 2) void gemm256p(
    const unsigned short* __restrict__ A, const unsigned short* __restrict__ B,
    int K,
    unsigned short* __restrict__ qbuf, unsigned short* __restrict__ kbuf,
    float* __restrict__ vout, unsigned short* __restrict__ vbT,
    const float* __restrict__ v1, const float* __restrict__ lambp,
    float* __restrict__ y, const float* __restrict__ bias,
    const float* __restrict__ cosT, const float* __restrict__ sinT)
{
    __shared__ __align__(16) char smem[131072];
    const int tid = threadIdx.x, lane = tid & 63, w = tid >> 6;
    const int wr = w >> 2, wc = w & 3;          // 2M x 4N waves
    const int lr = lane & 15, lh = lane >> 4;
    const long m0 = (long)blockIdx.x * 256;
    const long n0 = (long)blockIdx.y * 256;
    const int NT = K >> 6;                       // 16
    const long rsb = (long)K * 2;

    // per-lane global bases: row = m0/n0 + w*16 + lr, k-octet lh
    const char* pA = (const char*)A + (m0 + w * 16 + lr) * rsb + lh * 16;
    const char* pB = (const char*)B + (n0 + w * 16 + lr) * rsb + lh * 16;

    auto SA = [&](int t, int h) {                // stage A half-tile (2 gloads)
        char* dst = smem + (t & 1) * 65536 + (h * 8 + w) * 2048;
        const char* src = pA + (size_t)h * 128 * rsb + (size_t)t * 128;
        gload_lds16(src,      dst);
        gload_lds16(src + 64, dst + 1024);
    };
    auto SB = [&](int t, int h) {
        char* dst = smem + (t & 1) * 65536 + 32768 + (h * 8 + w) * 2048;
        const char* src = pB + (size_t)h * 128 * rsb + (size_t)t * 128;
        gload_lds16(src,      dst);
        gload_lds16(src + 64, dst + 1024);
    };

    const int fo = lh * 256 + lr * 16;
    f32x4 acc[8][4] = {};
    short8 af[4][2], bf[4][2];

    // prologue: B(0) both halves, A(0) both, B(1) both -> vmcnt(4) keeps B(1)
    SB(0, 0); SB(0, 1); SA(0, 0); SA(0, 1); SB(1, 0); SB(1, 1);
    WAIT_VM(4);
    BAR();
    FENCE();

    for (int t = 0; t < NT; ++t) {
        const char* ab = smem + (t & 1) * 65536;
        const char* bb = ab + 32768;

        // ---- P0: af[0-3], bf[0-1]; stage A0(t+1); MFMA m0-3 x n0-1 ----
        #pragma unroll
        for (int mi = 0; mi < 4; ++mi)
            #pragma unroll
            for (int ks = 0; ks < 2; ++ks)
                af[mi][ks] = *(const short8*)(ab + (wr * 8 + mi) * 2048 + ks * 1024 + fo);
        #pragma unroll
        for (int nj = 0; nj < 2; ++nj)
            #pragma unroll
            for (int ks = 0; ks < 2; ++ks)
                bf[nj][ks] = *(const short8*)(bb + (wc * 4 + nj) * 2048 + ks * 1024 + fo);
        if (t + 1 < NT) SA(t + 1, 0);
        BAR();
        WAIT_LGKM0();
        FENCE();
        __builtin_amdgcn_s_setprio(1);
        #pragma unroll
        for (int mi = 0; mi < 4; ++mi)
            #pragma unroll
            for (int nj = 0; nj < 2; ++nj)
                #pragma unroll
                for (int ks = 0; ks < 2; ++ks)
                    acc[mi][nj] = __builtin_amdgcn_mfma_f32_16x16x32_bf16(
                        af[mi][ks], bf[nj][ks], acc[mi][nj], 0, 0, 0);
        __builtin_amdgcn_s_setprio(0);
        BAR();

        // ---- P1: bf[2-3]; stage A1(t+1); MFMA m0-3 x n2-3 ----
        #pragma unroll
        for (int nj = 2; nj < 4; ++nj)
            #pragma unroll
            for (int ks = 0; ks < 2; ++ks)
                bf[nj][ks] = *(const short8*)(bb + (wc * 4 + nj) * 2048 + ks * 1024 + fo);
        if (t + 1 < NT) SA(t + 1, 1);
        BAR();
        WAIT_LGKM0();
        FENCE();
        __builtin_amdgcn_s_setprio(1);
        #pragma unroll
        for (int mi = 0; mi < 4; ++mi)
            #pragma unroll
            for (int nj = 2; nj < 4; ++nj)
                #pragma unroll
                for (int ks = 0; ks < 2; ++ks)
                    acc[mi][nj] = __builtin_amdgcn_mfma_f32_16x16x32_bf16(
                        af[mi][ks], bf[nj][ks], acc[mi][nj], 0, 0, 0);
        __builtin_amdgcn_s_setprio(0);
        BAR();

        // ---- P2: af[4-7] (reuse regs); stage B0(t+2); MFMA m4-7 x n0-1 ----
        #pragma unroll
        for (int mi = 0; mi < 4; ++mi)
            #pragma unroll
            for (int ks = 0; ks < 2; ++ks)
                af[mi][ks] = *(const short8*)(ab + (wr * 8 + 4 + mi) * 2048 + ks * 1024 + fo);
        if (t + 2 < NT) SB(t + 2, 0);
        BAR();
        WAIT_LGKM0();
        FENCE();
        __builtin_amdgcn_s_setprio(1);
        #pragma unroll
        for (int mi = 0; mi < 4; ++mi)
            #pragma unroll
            for (int nj = 0; nj < 2; ++nj)
                #pragma unroll
                for (int ks = 0; ks < 2; ++ks)
                    acc[mi + 4][nj] = __builtin_amdgcn_mfma_f32_16x16x32_bf16(
                        af[mi][ks], bf[nj][ks], acc[mi + 4][nj], 0, 0, 0);
        __builtin_amdgcn_s_setprio(0);
        BAR();

        // ---- P3: no reads; stage B1(t+2); vmcnt; MFMA m4-7 x n2-3 ----
        if (t + 2 < NT) { SB(t + 2, 1); WAIT_VM(4); }
        else            WAIT_VM(0);
        BAR();
        FENCE();
        __builtin_amdgcn_s_setprio(1);
        #pragma unroll
        for (int mi = 0; mi < 4; ++mi)
            #pragma unroll
            for (int nj = 2; nj < 4; ++nj)
                #pragma unroll
                for (int ks = 0; ks < 2; ++ks)
                    acc[mi + 4][nj] = __builtin_amdgcn_mfma_f32_16x16x32_bf16(
                        af[mi][ks], bf[nj][ks], acc[mi + 4][nj], 0, 0, 0);
        __builtin_amdgcn_s_setprio(0);
        BAR();
    }

    // ---- epilogue: per-wave 128 rows x 64 cols (verified in r6) ----
    if constexpr (MODE == 1) {
        const long nbase = n0 + wc * 64;      // wave-uniform, 64-aligned
        const int kk = (int)(nbase >> 10);    // 0=q 1=k 2=v (uniform)
        const int h = (int)((nbase & 1023) >> 6);
        if (kk == 2) {
            float lam = lambp[0];
            #pragma unroll
            for (int i = 0; i < 8; ++i)
            #pragma unroll
            for (int j = 0; j < 4; ++j)
            #pragma unroll
            for (int r = 0; r < 4; ++r) {
                long m = m0 + wr * 128 + i * 16 + lh * 4 + r;
                int d = j * 16 + lr;
                int rem = h * 64 + d;
                long b_ = m >> 11, t = m & 2047;
                size_t idx = (((size_t)(b_ * 16 + h)) * 2048 + t) * 64 + d;
                float vv = v1[(size_t)m * 1024 + rem];
                float val = (1.0f - lam) * acc[i][j][r] + lam * vv;
                vout[idx] = val;
                vbT[(((size_t)(b_ * 16 + h)) * 64 + d) * 2048 + t] = f2bf(val);
            }
        } else {
            unsigned short* dst = (kk == 0) ? qbuf : kbuf;
            #pragma unroll
            for (int i = 0; i < 8; ++i)
            #pragma unroll
            for (int r = 0; r < 4; ++r) {
                float v0 = acc[i][0][r], v1_ = acc[i][1][r];
                float v2 = acc[i][2][r], v3 = acc[i][3][r];
                float ss = v0 * v0 + v1_ * v1_ + v2 * v2 + v3 * v3;
                ss += __shfl_xor(ss, 1);
                ss += __shfl_xor(ss, 2);
                ss += __shfl_xor(ss, 4);
                ss += __shfl_xor(ss, 8);
                float inv = rsqrtf(ss * (1.0f / 64.0f) + 1e-6f);
                float x0f = v0 * inv, x1f = v1_ * inv;
                float x2f = v2 * inv, x3f = v3 * inv;
                long m = m0 + wr * 128 + i * 16 + lh * 4 + r;
                int t = (int)(m & 2047);
                long b_ = m >> 11;
                float c0 = cosT[t * 32 + lr],      s0 = sinT[t * 32 + lr];
                float c1 = cosT[t * 32 + 16 + lr], s1 = sinT[t * 32 + 16 + lr];
                size_t rb = (((size_t)(b_ * 16 + h)) * 2048 + t) * 64;
                dst[rb + 0 * 16 + lr] = f2bf( x0f * c0 + x2f * s0);
                dst[rb + 1 * 16 + lr] = f2bf( x1f * c1 + x3f * s1);
                dst[rb + 2 * 16 + lr] = f2bf(-x0f * s0 + x2f * c0);
                dst[rb + 3 * 16 + lr] = f2bf(-x1f * s1 + x3f * c1);
            }
        }
    } else {
        #pragma unroll
        for (int i = 0; i < 8; ++i)
        #pragma unroll
        for (int j = 0; j < 4; ++j)
        #pragma unroll
        for (int r = 0; r < 4; ++r) {
            long m = m0 + wr * 128 + i * 16 + lh * 4 + r;
            long n = n0 + wc * 64 + j * 16 + lr;
            y[(size_t)m * 1024 + n] = acc[i][j][r] + bias[n];
        }
    }
}

// ---------------- flash attention, sliding window (round-4 proven) -------
__global__ __launch_bounds__(512, 2) void attn_kernel(
    const unsigned short* __restrict__ qn, const unsigned short* __restrict__ kn,
    const unsigned short* __restrict__ vtb, unsigned short* __restrict__ attn_out,
    const int* __restrict__ winp)
{
    __shared__ unsigned short Ks[2][64 * 64];    // [key][d], swizzled
    __shared__ unsigned short Vt[2][64 * 64];    // [d][key], swizzled
    __shared__ unsigned short Pl[8][16 * 72];    // per-wave P: [qrow][key]
    const int tid = threadIdx.x, lane = tid & 63, w = tid >> 6;
    const int lr = lane & 15, lh = lane >> 4;
    const int bh = blockIdx.x;                   // 0..63
    const int qt2 = blockIdx.y;                  // 0..15
    const int t0 = qt2 * 128;
    const int win = winp[0];
    const int qrow = t0 + w * 16;

    short8 qf[2];
    #pragma unroll
    for (int ks = 0; ks < 2; ++ks)
        qf[ks] = *(const short8*)&qn[((size_t)bh * 2048 + qrow + lr) * 64 + ks * 32 + lh * 8];

    const int srow = tid >> 3;
    const int scol = (tid & 7) ^ (srow & 7);
    const char* kg = (const char*)kn + ((size_t)bh * 2048 + srow) * 128 + scol * 16;
    const char* vg = (const char*)vtb + ((size_t)(bh * 64 + srow)) * 4096 + scol * 16;
    char* lk = (char*)&Ks[0][0] + w * 1024;
    char* lv = (char*)&Vt[0][0] + w * 1024;

    auto STAGE = [&](int buf, int j0) {
        gload_lds16(kg + (size_t)j0 * 128, lk + buf * 8192);
        gload_lds16(vg + (size_t)j0 * 2,   lv + buf * 8192);
    };

    f32x4 oacc[4] = {};
    float mrow[4], lrow[4];
    #pragma unroll
    for (int r = 0; r < 4; ++r) { mrow[r] = -1e30f; lrow[r] = 0.f; }

    const float C = 0.125f * 1.44269504f;   // scale * log2(e)
    const int kvt0 = max(0, t0 - win + 1) >> 6;
    const int kvt1 = (t0 + 127) >> 6;

    STAGE(0, kvt0 * 64);
    __syncthreads();
    for (int kvt = kvt0; kvt <= kvt1; ++kvt) {
        const int j0 = kvt * 64;
        const int buf = (kvt - kvt0) & 1;
        if (kvt < kvt1) STAGE(buf ^ 1, j0 + 64);

        if (j0 <= qrow + 15 && j0 + 63 >= qrow + 16 - win) {
            const char* ksb = (const char*)&Ks[buf][0];
            const char* vtb_ = (const char*)&Vt[buf][0];

            float sv[4][4];
            #pragma unroll
            for (int kt = 0; kt < 4; ++kt) {
                f32x4 s = {};
                #pragma unroll
                for (int ks = 0; ks < 2; ++ks) {
                    int row = kt * 16 + lr;
                    int off = row * 128 + (((ks * 4 + lh) ^ (row & 7)) * 16);
                    short8 kf = *(const short8*)(ksb + off);
                    s = __builtin_amdgcn_mfma_f32_16x16x32_bf16(qf[ks], kf, s, 0, 0, 0);
                }
                #pragma unroll
                for (int r = 0; r < 4; ++r) {
                    int qi = qrow + lh * 4 + r;
                    int ji = j0 + kt * 16 + lr;
                    bool ok = (ji <= qi) && (qi - ji < win);
                    sv[kt][r] = ok ? s[r] * C : -1e30f;
                }
            }

            float pn[4][4];
            #pragma unroll
            for (int r = 0; r < 4; ++r) {
                float tm = fmaxf(fmaxf(sv[0][r], sv[1][r]), fmaxf(sv[2][r], sv[3][r]));
                #pragma unroll
                for (int m = 1; m < 16; m <<= 1) tm = fmaxf(tm, __shfl_xor(tm, m));
                float nm = fmaxf(mrow[r], tm);
                float alpha = exp2f(mrow[r] - nm);
                float ps = 0.f;
                #pragma unroll
                for (int kt = 0; kt < 4; ++kt) {
                    float p = exp2f(sv[kt][r] - nm);
                    pn[kt][r] = p; ps += p;
                }
                #pragma unroll
                for (int m = 1; m < 16; m <<= 1) ps += __shfl_xor(ps, m);
                lrow[r] = lrow[r] * alpha + ps;
                mrow[r] = nm;
                #pragma unroll
                for (int dt = 0; dt < 4; ++dt) oacc[dt][r] *= alpha;
            }

            #pragma unroll
            for (int kt = 0; kt < 4; ++kt)
                #pragma unroll
                for (int r = 0; r < 4; ++r)
                    Pl[w][(lh * 4 + r) * 72 + kt * 16 + lr] = f2bf(pn[kt][r]);

            short8 pf[2];
            #pragma unroll
            for (int ks = 0; ks < 2; ++ks)
                pf[ks] = *(const short8*)&Pl[w][lr * 72 + ks * 32 + lh * 8];
            #pragma unroll
            for (int dt = 0; dt < 4; ++dt)
                #pragma unroll
                for (int ks = 0; ks < 2; ++ks) {
                    int row = dt * 16 + lr;
                    int off = row * 128 + (((ks * 4 + lh) ^ (row & 7)) * 16);
                    short8 vf = *(const short8*)(vtb_ + off);
                    oacc[dt] = __builtin_amdgcn_mfma_f32_16x16x32_bf16(pf[ks], vf, oacc[dt], 0, 0, 0);
                }
        }
        __syncthreads();
    }

    int b = bh >> 4, h = bh & 15;
    #pragma unroll
    for (int dt = 0; dt < 4; ++dt)
        #pragma unroll
        for (int r = 0; r < 4; ++r) {
            int t = qrow + lh * 4 + r;
            float o = oacc[dt][r] / lrow[r];
            attn_out[((size_t)b * 2048 + t) * 1024 + h * 64 + dt * 16 + lr] = f2bf(o);
        }
}

extern "C" void kernel_launch(void* const* d_in, const int* in_sizes, int n_in,
                              void* d_out, int out_size, void* d_ws, size_t ws_size,
                              hipStream_t stream) {
    const float* x    = (const float*)d_in[0];
    const float* v1   = (const float*)d_in[1];
    const float* qkvw = (const float*)d_in[2];
    const float* cpw  = (const float*)d_in[3];
    const float* cpb  = (const float*)d_in[4];
    const float* lamb = (const float*)d_in[5];
    const int*   winp = (const int*)d_in[6];

    float* y    = (float*)d_out;
    float* vout = y + (size_t)8192 * 1024;   // value output (B,H,T,64) fp32

    // V^T bf16 scratch lives in the y region of d_out; proj overwrites y after.
    unsigned short* vbT = (unsigned short*)y;

    char* ws = (char*)d_ws;
    unsigned short* xb   = (unsigned short*)(ws);                 // 16MB (reused as attn_out)
    unsigned short* Wb   = (unsigned short*)(ws + (16u << 20));   // 6MB
    unsigned short* Wp   = (unsigned short*)(ws + (22u << 20));   // 2MB
    unsigned short* qbuf = (unsigned short*)(ws + (24u << 20));   // 16MB
    unsigned short* kbuf = (unsigned short*)(ws + (40u << 20));   // 16MB
    float* cosT = (float*)(ws + (56u << 20));                     // 256KB
    float* sinT = (float*)(ws + (56u << 20) + (256u << 10));      // 256KB

    cvt3_kernel<<<12288, 256, 0, stream>>>(x, qkvw, cpw, xb, Wb, Wp);
    rope_tables<<<65536 / 256, 256, 0, stream>>>(cosT, sinT);

    gemm256p<1><<<dim3(32, 12), 512, 0, stream>>>(xb, Wb, 1024,
        qbuf, kbuf, vout, vbT, v1, lamb, nullptr, nullptr, cosT, sinT);

    attn_kernel<<<dim3(64, 16), 512, 0, stream>>>(qbuf, kbuf, vbT, xb, winp);

    gemm256p<2><<<dim3(32, 4), 512, 0, stream>>>(xb, Wp, 1024,
        nullptr, nullptr, nullptr, nullptr, nullptr, nullptr, y, cpb, nullptr, nullptr);
}